// Round 1
// baseline (559.434 us; speedup 1.0000x reference)
//
#include <hip/hip_runtime.h>
#include <stdint.h>

#define NH 16
#define DK 64
#define BB 16
#define SS 512
#define DM 1024
#define DFF 4096

typedef __attribute__((ext_vector_type(8))) __bf16 bf16x8;
typedef __attribute__((ext_vector_type(4))) float  float4v;

__device__ __forceinline__ unsigned short f2bf(float f) {
  union { float f; unsigned int u; } v; v.f = f;
  unsigned int u = v.u + 0x7fffu + ((v.u >> 16) & 1u);
  return (unsigned short)(u >> 16);
}

__device__ __forceinline__ void gld_lds16(const void* g, void* l) {
  __builtin_amdgcn_global_load_lds(
      (const __attribute__((address_space(1))) unsigned int*)g,
      (__attribute__((address_space(3))) unsigned int*)l, 16, 0, 0);
}

// ---------------- weight transpose+convert: in fp32 [R][C] -> out bf16 [C][R]
__global__ void transpose_bf16(const float* __restrict__ in, unsigned short* __restrict__ out,
                               int R, int C) {
  __shared__ float tile[32][33];
  int c0 = blockIdx.x * 32, r0 = blockIdx.y * 32;
  int tx = threadIdx.x, ty = threadIdx.y;
  for (int j = ty; j < 32; j += 8)
    tile[j][tx] = in[(size_t)(r0 + j) * C + c0 + tx];
  __syncthreads();
  for (int j = ty; j < 32; j += 8)
    out[(size_t)(c0 + j) * R + r0 + tx] = f2bf(tile[tx][j]);
}

// ---------------- layernorm: fp32 [rows][1024] -> bf16
__global__ __launch_bounds__(256) void ln_bf16(const float* __restrict__ in,
                                               const float* __restrict__ g,
                                               const float* __restrict__ be,
                                               unsigned short* __restrict__ out) {
  int row = blockIdx.x, t = threadIdx.x;
  const float4* in4 = (const float4*)(in + (size_t)row * DM);
  float4 v = in4[t];
  float s  = v.x + v.y + v.z + v.w;
  float s2 = v.x * v.x + v.y * v.y + v.z * v.z + v.w * v.w;
  for (int off = 1; off < 64; off <<= 1) { s += __shfl_xor(s, off); s2 += __shfl_xor(s2, off); }
  __shared__ float rs[4], rs2[4];
  int wave = t >> 6;
  if ((t & 63) == 0) { rs[wave] = s; rs2[wave] = s2; }
  __syncthreads();
  s  = rs[0] + rs[1] + rs[2] + rs[3];
  s2 = rs2[0] + rs2[1] + rs2[2] + rs2[3];
  float mu = s * (1.f / DM);
  float var = s2 * (1.f / DM) - mu * mu;
  float rstd = rsqrtf(var + 1e-5f);
  float4 gv = ((const float4*)g)[t];
  float4 bv = ((const float4*)be)[t];
  unsigned short o0 = f2bf((v.x - mu) * rstd * gv.x + bv.x);
  unsigned short o1 = f2bf((v.y - mu) * rstd * gv.y + bv.y);
  unsigned short o2 = f2bf((v.z - mu) * rstd * gv.z + bv.z);
  unsigned short o3 = f2bf((v.w - mu) * rstd * gv.w + bv.w);
  uint2 pk; pk.x = o0 | ((unsigned)o1 << 16); pk.y = o2 | ((unsigned)o3 << 16);
  *(uint2*)(out + (size_t)row * DM + t * 4) = pk;
}

// ---------------- GEMM C[M,N] = A[M,K] * Bt[N,K]^T, m97 structure
// MODE 0: QKV scatter (qo/ko/vo)  1: outf = resid + acc
// MODE 2: outb = bf16(relu(acc+bias))  3: outf = resid + acc + bias
template <int MODE>
__global__ __launch_bounds__(256, 2)
void gemm_bt(const unsigned short* __restrict__ A, const unsigned short* __restrict__ Bt,
             int M, int N, int K,
             const float* __restrict__ bias, const float* __restrict__ resid,
             float* __restrict__ outf, unsigned short* __restrict__ outb,
             unsigned short* __restrict__ qo, unsigned short* __restrict__ ko,
             unsigned short* __restrict__ vo) {
  __shared__ __align__(16) unsigned short As[128 * 32];
  __shared__ __align__(16) unsigned short Bs[128 * 32];
  const int t = threadIdx.x, lane = t & 63, wave = t >> 6;
  const int lc = lane & 15, lr = lane >> 4;
  const int wm = wave >> 1, wn = wave & 1;
  const int rowblk = blockIdx.y * 128, colblk = blockIdx.x * 128;

  float4v acc[4][4];
#pragma unroll
  for (int i = 0; i < 4; i++)
#pragma unroll
    for (int j = 0; j < 4; j++) acc[i][j] = (float4v)0.f;

  const int r0 = t >> 2;            // row within 64-row chunk
  const int k8 = (t & 3) * 8;       // element offset in row

  for (int k0 = 0; k0 < K; k0 += 32) {
#pragma unroll
    for (int c = 0; c < 2; c++) {
      int row = c * 64 + r0;
      gld_lds16(A  + (size_t)(rowblk + row) * K + k0 + k8, &As[row * 32 + k8]);
      gld_lds16(Bt + (size_t)(colblk + row) * K + k0 + k8, &Bs[row * 32 + k8]);
    }
    __syncthreads();
    bf16x8 af[4], bfr[4];
#pragma unroll
    for (int mt = 0; mt < 4; mt++)
      af[mt] = *(const bf16x8*)&As[(wm * 64 + mt * 16 + lc) * 32 + lr * 8];
#pragma unroll
    for (int nt = 0; nt < 4; nt++)
      bfr[nt] = *(const bf16x8*)&Bs[(wn * 64 + nt * 16 + lc) * 32 + lr * 8];
#pragma unroll
    for (int mt = 0; mt < 4; mt++)
#pragma unroll
      for (int nt = 0; nt < 4; nt++)
        acc[mt][nt] = __builtin_amdgcn_mfma_f32_16x16x32_bf16(af[mt], bfr[nt], acc[mt][nt], 0, 0, 0);
    __syncthreads();
  }

#pragma unroll
  for (int mt = 0; mt < 4; mt++)
#pragma unroll
    for (int nt = 0; nt < 4; nt++)
#pragma unroll
      for (int r = 0; r < 4; r++) {
        int row = rowblk + wm * 64 + mt * 16 + lr * 4 + r;
        int col = colblk + wn * 64 + nt * 16 + lc;
        float v = acc[mt][nt][r];
        if (MODE == 0) {
          int b = row >> 9, s = row & 511;
          int f = col & 1023, h = f >> 6, d = f & 63;
          if (col < 1024)
            qo[(((size_t)b * NH + h) * SS + s) * DK + d] = f2bf(v);
          else if (col < 2048)
            ko[(((size_t)b * NH + h) * SS + s) * DK + d] = f2bf(v);
          else
            vo[(((size_t)b * NH + h) * DK + d) * SS + s] = f2bf(v);
        } else if (MODE == 1) {
          outf[(size_t)row * N + col] = resid[(size_t)row * N + col] + v;
        } else if (MODE == 2) {
          outb[(size_t)row * N + col] = f2bf(fmaxf(v + bias[col], 0.f));
        } else {
          outf[(size_t)row * N + col] = resid[(size_t)row * N + col] + v + bias[col];
        }
      }
}

// ---------------- flash attention, causal, 1 block = (b, h, 128 q-rows)
__global__ __launch_bounds__(256, 2)
void attn(const unsigned short* __restrict__ Qb, const unsigned short* __restrict__ Kb,
          const unsigned short* __restrict__ Vtb, unsigned short* __restrict__ Ob) {
  __shared__ __align__(16) unsigned short Qs[128 * 64];
  __shared__ __align__(16) unsigned short Ks[128 * 64];
  __shared__ __align__(16) unsigned short Vts[64 * 128];
  __shared__ __align__(16) unsigned short Ps[4 * 32 * 128];
  const int t = threadIdx.x, lane = t & 63, wave = t >> 6;
  const int lc = lane & 15, lr = lane >> 4;
  const int qt = blockIdx.x, h = blockIdx.y, b = blockIdx.z;
  const int Q0 = qt * 128;
  const size_t headQK = ((size_t)b * NH + h) * SS * DK;
  const size_t headV  = ((size_t)b * NH + h) * DK * SS;
  const float SCALE = 0.125f, L2E = 1.44269504f;

  // stage Q tile [128][64] (contiguous 16KB)
  {
    const unsigned short* gq = Qb + headQK + (size_t)Q0 * DK;
#pragma unroll
    for (int c = 0; c < 4; c++)
      gld_lds16(gq + c * 2048 + t * 8, &Qs[c * 2048 + t * 8]);
  }

  float4v o_acc[2][4];
#pragma unroll
  for (int mt = 0; mt < 2; mt++)
#pragma unroll
    for (int nt = 0; nt < 4; nt++) o_acc[mt][nt] = (float4v)0.f;
  float m_i[2][4], l_i[2][4];
#pragma unroll
  for (int mt = 0; mt < 2; mt++)
#pragma unroll
    for (int r = 0; r < 4; r++) { m_i[mt][r] = -__builtin_inff(); l_i[mt][r] = 0.f; }

  for (int kt = 0; kt <= qt; kt++) {
    __syncthreads();  // previous tile fully consumed
    const unsigned short* gk = Kb + headQK + (size_t)kt * 128 * DK;
#pragma unroll
    for (int c = 0; c < 4; c++)
      gld_lds16(gk + c * 2048 + t * 8, &Ks[c * 2048 + t * 8]);
#pragma unroll
    for (int c = 0; c < 4; c++) {
      int e = c * 2048 + t * 8;
      int d = e >> 7, cl = e & 127;
      gld_lds16(Vtb + headV + (size_t)d * SS + kt * 128 + cl, &Vts[e]);
    }
    __syncthreads();  // staging complete (vmcnt drained at barrier)

    // S = Q K^T  (wave's 32 q-rows x 128 kpos)
    float4v s[2][8];
#pragma unroll
    for (int mt = 0; mt < 2; mt++)
#pragma unroll
      for (int nt = 0; nt < 8; nt++) s[mt][nt] = (float4v)0.f;
#pragma unroll
    for (int kk = 0; kk < 2; kk++) {
      bf16x8 aq[2];
#pragma unroll
      for (int mt = 0; mt < 2; mt++)
        aq[mt] = *(const bf16x8*)&Qs[(wave * 32 + mt * 16 + lc) * 64 + kk * 32 + lr * 8];
#pragma unroll
      for (int nt = 0; nt < 8; nt++) {
        bf16x8 bk = *(const bf16x8*)&Ks[(nt * 16 + lc) * 64 + kk * 32 + lr * 8];
#pragma unroll
        for (int mt = 0; mt < 2; mt++)
          s[mt][nt] = __builtin_amdgcn_mfma_f32_16x16x32_bf16(aq[mt], bk, s[mt][nt], 0, 0, 0);
      }
    }
    const bool diag = (kt == qt);
#pragma unroll
    for (int mt = 0; mt < 2; mt++)
#pragma unroll
      for (int nt = 0; nt < 8; nt++)
#pragma unroll
        for (int r = 0; r < 4; r++) {
          float sv = s[mt][nt][r] * SCALE;
          if (diag && (nt * 16 + lc > wave * 32 + mt * 16 + lr * 4 + r)) sv = -__builtin_inff();
          s[mt][nt][r] = sv;
        }
    // online softmax
    float alpha_a[2][4];
#pragma unroll
    for (int mt = 0; mt < 2; mt++)
#pragma unroll
      for (int r = 0; r < 4; r++) {
        float mx = -__builtin_inff();
#pragma unroll
        for (int nt = 0; nt < 8; nt++) mx = fmaxf(mx, s[mt][nt][r]);
        for (int off = 1; off < 16; off <<= 1) mx = fmaxf(mx, __shfl_xor(mx, off));
        float mnew = fmaxf(m_i[mt][r], mx);
        float alpha = exp2f((m_i[mt][r] - mnew) * L2E);
        m_i[mt][r] = mnew;
        float rsum = 0.f;
#pragma unroll
        for (int nt = 0; nt < 8; nt++) {
          float p = exp2f((s[mt][nt][r] - mnew) * L2E);
          s[mt][nt][r] = p;
          rsum += p;
        }
        for (int off = 1; off < 16; off <<= 1) rsum += __shfl_xor(rsum, off);
        l_i[mt][r] = l_i[mt][r] * alpha + rsum;
        alpha_a[mt][r] = alpha;
      }
    // rescale O
#pragma unroll
    for (int mt = 0; mt < 2; mt++)
#pragma unroll
      for (int nt = 0; nt < 4; nt++)
#pragma unroll
        for (int r = 0; r < 4; r++) o_acc[mt][nt][r] *= alpha_a[mt][r];
    // P -> LDS (C-layout to A-layout round trip)
    const int wbase = wave * 32 * 128;
#pragma unroll
    for (int mt = 0; mt < 2; mt++)
#pragma unroll
      for (int nt = 0; nt < 8; nt++)
#pragma unroll
        for (int r = 0; r < 4; r++)
          Ps[wbase + (mt * 16 + lr * 4 + r) * 128 + nt * 16 + lc] = f2bf(s[mt][nt][r]);
    // O += P V   (LDS ops within a wave are in-order)
#pragma unroll
    for (int kk = 0; kk < 4; kk++) {
      bf16x8 ap[2];
#pragma unroll
      for (int mt = 0; mt < 2; mt++)
        ap[mt] = *(const bf16x8*)&Ps[wbase + (mt * 16 + lc) * 128 + kk * 32 + lr * 8];
#pragma unroll
      for (int nt = 0; nt < 4; nt++) {
        bf16x8 bv = *(const bf16x8*)&Vts[(nt * 16 + lc) * 128 + kk * 32 + lr * 8];
#pragma unroll
        for (int mt = 0; mt < 2; mt++)
          o_acc[mt][nt] = __builtin_amdgcn_mfma_f32_16x16x32_bf16(ap[mt], bv, o_acc[mt][nt], 0, 0, 0);
      }
    }
  }
  // normalize + store to [b, s, h*64+d]
  float inv[2][4];
#pragma unroll
  for (int mt = 0; mt < 2; mt++)
#pragma unroll
    for (int r = 0; r < 4; r++) inv[mt][r] = 1.f / l_i[mt][r];
#pragma unroll
  for (int mt = 0; mt < 2; mt++)
#pragma unroll
    for (int nt = 0; nt < 4; nt++)
#pragma unroll
      for (int r = 0; r < 4; r++) {
        int sg = Q0 + wave * 32 + mt * 16 + lr * 4 + r;
        int col = h * DK + nt * 16 + lc;
        Ob[((size_t)b * SS + sg) * DM + col] = f2bf(o_acc[mt][nt][r] * inv[mt][r]);
      }
}

extern "C" void kernel_launch(void* const* d_in, const int* in_sizes, int n_in,
                              void* d_out, int out_size, void* d_ws, size_t ws_size,
                              hipStream_t stream) {
  const float* x  = (const float*)d_in[0];
  const float* Wq = (const float*)d_in[1];
  const float* Wk = (const float*)d_in[2];
  const float* Wv = (const float*)d_in[3];
  const float* Wo = (const float*)d_in[4];
  const float* W1 = (const float*)d_in[5];
  const float* b1 = (const float*)d_in[6];
  const float* W2 = (const float*)d_in[7];
  const float* b2 = (const float*)d_in[8];
  const float* g1 = (const float*)d_in[9];
  const float* be1 = (const float*)d_in[10];
  const float* g2 = (const float*)d_in[11];
  const float* be2 = (const float*)d_in[12];

  char* ws = (char*)d_ws;
  unsigned short* WqkvT = (unsigned short*)(ws);                 // 6 MB
  unsigned short* WoT   = (unsigned short*)(ws + 6291456);       // 2 MB
  unsigned short* W1T   = (unsigned short*)(ws + 8388608);       // 8 MB
  unsigned short* W2T   = (unsigned short*)(ws + 16777216);      // 8 MB
  unsigned short* hbuf  = (unsigned short*)(ws + 25165824);      // 16 MB
  unsigned short* Qb    = (unsigned short*)(ws + 41943040);      // 16 MB
  unsigned short* Kb    = (unsigned short*)(ws + 58720256);      // 16 MB
  unsigned short* Vtb   = (unsigned short*)(ws + 75497472);      // 16 MB
  unsigned short* attnO = (unsigned short*)(ws + 92274688);      // 16 MB
  float*          x1    = (float*)(ws + 109051904);              // 32 MB
  unsigned short* ffn1  = (unsigned short*)(ws + 41943040);      // 64 MB, aliases Qb..attnO (dead)

  dim3 tb(32, 8);
  transpose_bf16<<<dim3(32, 32), tb, 0, stream>>>(Wq, WqkvT, 1024, 1024);
  transpose_bf16<<<dim3(32, 32), tb, 0, stream>>>(Wk, WqkvT + 1024 * 1024, 1024, 1024);
  transpose_bf16<<<dim3(32, 32), tb, 0, stream>>>(Wv, WqkvT + 2048 * 1024, 1024, 1024);
  transpose_bf16<<<dim3(32, 32), tb, 0, stream>>>(Wo, WoT, 1024, 1024);
  transpose_bf16<<<dim3(128, 32), tb, 0, stream>>>(W1, W1T, 1024, 4096);
  transpose_bf16<<<dim3(32, 128), tb, 0, stream>>>(W2, W2T, 4096, 1024);

  ln_bf16<<<8192, 256, 0, stream>>>(x, g1, be1, hbuf);

  gemm_bt<0><<<dim3(24, 64), 256, 0, stream>>>(hbuf, WqkvT, 8192, 3072, 1024,
      nullptr, nullptr, nullptr, nullptr, Qb, Kb, Vtb);

  attn<<<dim3(4, NH, BB), 256, 0, stream>>>(Qb, Kb, Vtb, attnO);

  gemm_bt<1><<<dim3(8, 64), 256, 0, stream>>>(attnO, WoT, 8192, 1024, 1024,
      nullptr, x, x1, nullptr, nullptr, nullptr, nullptr);

  ln_bf16<<<8192, 256, 0, stream>>>(x1, g2, be2, hbuf);

  gemm_bt<2><<<dim3(32, 64), 256, 0, stream>>>(hbuf, W1T, 8192, 4096, 1024,
      b1, nullptr, nullptr, ffn1, nullptr, nullptr, nullptr);

  gemm_bt<3><<<dim3(8, 64), 256, 0, stream>>>(ffn1, W2T, 8192, 1024, 4096,
      b2, x1, (float*)d_out, nullptr, nullptr, nullptr, nullptr);
}

// Round 2
// 504.067 us; speedup vs baseline: 1.1098x; 1.1098x over previous
//
#include <hip/hip_runtime.h>
#include <stdint.h>

#define NH 16
#define DK 64
#define BB 16
#define SS 512
#define DM 1024
#define DFF 4096

typedef __attribute__((ext_vector_type(8))) __bf16 bf16x8;
typedef __attribute__((ext_vector_type(4))) float  float4v;

__device__ __forceinline__ unsigned short f2bf(float f) {
  union { float f; unsigned int u; } v; v.f = f;
  unsigned int u = v.u + 0x7fffu + ((v.u >> 16) & 1u);
  return (unsigned short)(u >> 16);
}

__device__ __forceinline__ void gld_lds16(const void* g, void* l) {
  __builtin_amdgcn_global_load_lds(
      (const __attribute__((address_space(1))) unsigned int*)g,
      (__attribute__((address_space(3))) unsigned int*)l, 16, 0, 0);
}

// ---------------- all weight transposes fused: fp32 [R][C] -> bf16 [C][R]
__global__ void transpose_all(const float* __restrict__ Wq, const float* __restrict__ Wk,
                              const float* __restrict__ Wv, const float* __restrict__ Wo,
                              const float* __restrict__ W1, const float* __restrict__ W2,
                              unsigned short* __restrict__ WqkvT, unsigned short* __restrict__ WoT,
                              unsigned short* __restrict__ W1T, unsigned short* __restrict__ W2T) {
  __shared__ float tile[32][33];
  int bid = blockIdx.x;
  const float* in; unsigned short* out; int R, C, tl;
  if (bid < 1024)      { in = Wq; out = WqkvT;            R = 1024; C = 1024; tl = bid; }
  else if (bid < 2048) { in = Wk; out = WqkvT + 1048576;  R = 1024; C = 1024; tl = bid - 1024; }
  else if (bid < 3072) { in = Wv; out = WqkvT + 2097152;  R = 1024; C = 1024; tl = bid - 2048; }
  else if (bid < 4096) { in = Wo; out = WoT;              R = 1024; C = 1024; tl = bid - 3072; }
  else if (bid < 8192) { in = W1; out = W1T;              R = 1024; C = 4096; tl = bid - 4096; }
  else                 { in = W2; out = W2T;              R = 4096; C = 1024; tl = bid - 8192; }
  int ntx = C >> 5;
  int c0 = (tl % ntx) * 32, r0 = (tl / ntx) * 32;
  int tx = threadIdx.x, ty = threadIdx.y;
  for (int j = ty; j < 32; j += 8)
    tile[j][tx] = in[(size_t)(r0 + j) * C + c0 + tx];
  __syncthreads();
  for (int j = ty; j < 32; j += 8)
    out[(size_t)(c0 + j) * R + r0 + tx] = f2bf(tile[tx][j]);
}

// ---------------- layernorm: fp32 [rows][1024] -> bf16
__global__ __launch_bounds__(256) void ln_bf16(const float* __restrict__ in,
                                               const float* __restrict__ g,
                                               const float* __restrict__ be,
                                               unsigned short* __restrict__ out) {
  int row = blockIdx.x, t = threadIdx.x;
  const float4* in4 = (const float4*)(in + (size_t)row * DM);
  float4 v = in4[t];
  float s  = v.x + v.y + v.z + v.w;
  float s2 = v.x * v.x + v.y * v.y + v.z * v.z + v.w * v.w;
  for (int off = 1; off < 64; off <<= 1) { s += __shfl_xor(s, off); s2 += __shfl_xor(s2, off); }
  __shared__ float rs[4], rs2[4];
  int wave = t >> 6;
  if ((t & 63) == 0) { rs[wave] = s; rs2[wave] = s2; }
  __syncthreads();
  s  = rs[0] + rs[1] + rs[2] + rs[3];
  s2 = rs2[0] + rs2[1] + rs2[2] + rs2[3];
  float mu = s * (1.f / DM);
  float var = s2 * (1.f / DM) - mu * mu;
  float rstd = rsqrtf(var + 1e-5f);
  float4 gv = ((const float4*)g)[t];
  float4 bv = ((const float4*)be)[t];
  unsigned short o0 = f2bf((v.x - mu) * rstd * gv.x + bv.x);
  unsigned short o1 = f2bf((v.y - mu) * rstd * gv.y + bv.y);
  unsigned short o2 = f2bf((v.z - mu) * rstd * gv.z + bv.z);
  unsigned short o3 = f2bf((v.w - mu) * rstd * gv.w + bv.w);
  uint2 pk; pk.x = o0 | ((unsigned)o1 << 16); pk.y = o2 | ((unsigned)o3 << 16);
  *(uint2*)(out + (size_t)row * DM + t * 4) = pk;
}

// ---------------- GEMM C[M,N] = A[M,K] * Bt[N,K]^T, m97 structure
// LDS layout: per 64B row of 4 16B granules, granule g stored at slot g^((row>>1)&3)
// (staging permutes the SOURCE granule so LDS dst stays lane-contiguous; fragment
//  reads XOR the slot -> 2-way bank aliasing = free, was 8-way)
// MODE 0: QKV scatter (qo/ko/vo)  1: outf = resid + acc
// MODE 2: outb = bf16(relu(acc+bias))  3: outf = resid + acc + bias
template <int MODE>
__global__ __launch_bounds__(256, 2)
void gemm_bt(const unsigned short* __restrict__ A, const unsigned short* __restrict__ Bt,
             int M, int N, int K,
             const float* __restrict__ bias, const float* __restrict__ resid,
             float* __restrict__ outf, unsigned short* __restrict__ outb,
             unsigned short* __restrict__ qo, unsigned short* __restrict__ ko,
             unsigned short* __restrict__ vo) {
  __shared__ __align__(16) unsigned short As[128 * 32];
  __shared__ __align__(16) unsigned short Bs[128 * 32];
  const int t = threadIdx.x, lane = t & 63, wave = t >> 6;
  const int lc = lane & 15, lr = lane >> 4;
  const int wm = wave >> 1, wn = wave & 1;

  // group-major (GM=8) block swizzle: each XCD pins one M-row-tile, streams N
  const int nbn = gridDim.x;
  int pid = blockIdx.y * nbn + blockIdx.x;
  int nig = nbn << 3;
  int gid = pid / nig;
  int loc = pid - gid * nig;
  const int rowblk = (gid * 8 + (loc & 7)) * 128;
  const int colblk = (loc >> 3) * 128;

  float4v acc[4][4];
#pragma unroll
  for (int i = 0; i < 4; i++)
#pragma unroll
    for (int j = 0; j < 4; j++) acc[i][j] = (float4v)0.f;

  const int r0 = t >> 2;                      // row within 64-row chunk
  const int sg = ((t & 3) ^ ((r0 >> 1) & 3)); // swizzled source granule
  const int ldsoff = r0 * 32 + (t & 3) * 8;   // lane-contiguous dst
  const int goff = sg * 8;

  for (int k0 = 0; k0 < K; k0 += 32) {
#pragma unroll
    for (int c = 0; c < 2; c++) {
      int row = c * 64 + r0;
      gld_lds16(A  + (size_t)(rowblk + row) * K + k0 + goff, &As[c * 2048 + ldsoff]);
      gld_lds16(Bt + (size_t)(colblk + row) * K + k0 + goff, &Bs[c * 2048 + ldsoff]);
    }
    __syncthreads();
    bf16x8 af[4], bfr[4];
    const int slot = (lr ^ ((lc >> 1) & 3)) * 8;
#pragma unroll
    for (int mt = 0; mt < 4; mt++)
      af[mt] = *(const bf16x8*)&As[(wm * 64 + mt * 16 + lc) * 32 + slot];
#pragma unroll
    for (int nt = 0; nt < 4; nt++)
      bfr[nt] = *(const bf16x8*)&Bs[(wn * 64 + nt * 16 + lc) * 32 + slot];
#pragma unroll
    for (int mt = 0; mt < 4; mt++)
#pragma unroll
      for (int nt = 0; nt < 4; nt++)
        acc[mt][nt] = __builtin_amdgcn_mfma_f32_16x16x32_bf16(af[mt], bfr[nt], acc[mt][nt], 0, 0, 0);
    __syncthreads();
  }

#pragma unroll
  for (int mt = 0; mt < 4; mt++)
#pragma unroll
    for (int nt = 0; nt < 4; nt++)
#pragma unroll
      for (int r = 0; r < 4; r++) {
        int row = rowblk + wm * 64 + mt * 16 + lr * 4 + r;
        int col = colblk + wn * 64 + nt * 16 + lc;
        float v = acc[mt][nt][r];
        if (MODE == 0) {
          int b = row >> 9, s = row & 511;
          int f = col & 1023, h = f >> 6, d = f & 63;
          if (col < 1024)
            qo[(((size_t)b * NH + h) * SS + s) * DK + d] = f2bf(v);
          else if (col < 2048)
            ko[(((size_t)b * NH + h) * SS + s) * DK + d] = f2bf(v);
          else
            vo[(((size_t)b * NH + h) * DK + d) * SS + s] = f2bf(v);
        } else if (MODE == 1) {
          outf[(size_t)row * N + col] = resid[(size_t)row * N + col] + v;
        } else if (MODE == 2) {
          outb[(size_t)row * N + col] = f2bf(fmaxf(v + bias[col], 0.f));
        } else {
          outf[(size_t)row * N + col] = resid[(size_t)row * N + col] + v + bias[col];
        }
      }
}

// ---------------- flash attention, causal, 1 block = (b, h, 128 q-rows)
// LDS swizzle: Qs/Ks rows have 8 granules, Vts/Ps rows 16; granule g stored at
// slot g^(row&7) -> all fragment reads 2-way (were 16-way conflicted).
__global__ __launch_bounds__(256, 2)
void attn(const unsigned short* __restrict__ Qb, const unsigned short* __restrict__ Kb,
          const unsigned short* __restrict__ Vtb, unsigned short* __restrict__ Ob) {
  __shared__ __align__(16) unsigned short Qs[128 * 64];
  __shared__ __align__(16) unsigned short Ks[128 * 64];
  __shared__ __align__(16) unsigned short Vts[64 * 128];
  __shared__ __align__(16) unsigned short Ps[4 * 32 * 128];
  const int t = threadIdx.x, lane = t & 63, wave = t >> 6;
  const int lc = lane & 15, lr = lane >> 4;
  const int qt = blockIdx.x, h = blockIdx.y, b = blockIdx.z;
  const int Q0 = qt * 128;
  const size_t headQK = ((size_t)b * NH + h) * SS * DK;
  const size_t headV  = ((size_t)b * NH + h) * DK * SS;
  const float SCALE = 0.125f, L2E = 1.44269504f;

  // staging swizzle offsets (Q/K: row=t>>3, slot=t&7; V: row=t>>4, slot=t&15)
  const int qkg = ((t & 7) ^ ((t >> 3) & 7)) * 8;   // source granule offset, elements
  const int qkrow = (t >> 3) * 64;                  // source row offset, elements
  const int vg = ((t & 15) ^ ((t >> 4) & 7)) * 8;
  const int vrow = t >> 4;                          // d within 16-row chunk

  // stage Q tile [128][64]
  {
    const unsigned short* gq = Qb + headQK + (size_t)Q0 * DK;
#pragma unroll
    for (int c = 0; c < 4; c++)
      gld_lds16(gq + c * 2048 + qkrow + qkg, &Qs[c * 2048 + t * 8]);
  }

  float4v o_acc[2][4];
#pragma unroll
  for (int mt = 0; mt < 2; mt++)
#pragma unroll
    for (int nt = 0; nt < 4; nt++) o_acc[mt][nt] = (float4v)0.f;
  float m_i[2][4], l_i[2][4];
#pragma unroll
  for (int mt = 0; mt < 2; mt++)
#pragma unroll
    for (int r = 0; r < 4; r++) { m_i[mt][r] = -__builtin_inff(); l_i[mt][r] = 0.f; }

  for (int kt = 0; kt <= qt; kt++) {
    __syncthreads();  // previous tile fully consumed (also orders Q staging)
    const unsigned short* gk = Kb + headQK + (size_t)kt * 128 * DK;
#pragma unroll
    for (int c = 0; c < 4; c++)
      gld_lds16(gk + c * 2048 + qkrow + qkg, &Ks[c * 2048 + t * 8]);
#pragma unroll
    for (int c = 0; c < 4; c++) {
      int d = c * 16 + vrow;
      gld_lds16(Vtb + headV + (size_t)d * SS + kt * 128 + vg, &Vts[c * 2048 + t * 8]);
    }
    __syncthreads();  // staging complete

    // S = Q K^T  (wave's 32 q-rows x 128 kpos)
    float4v s[2][8];
#pragma unroll
    for (int mt = 0; mt < 2; mt++)
#pragma unroll
      for (int nt = 0; nt < 8; nt++) s[mt][nt] = (float4v)0.f;
#pragma unroll
    for (int kk = 0; kk < 2; kk++) {
      bf16x8 aq[2];
#pragma unroll
      for (int mt = 0; mt < 2; mt++) {
        int row = wave * 32 + mt * 16 + lc;
        aq[mt] = *(const bf16x8*)&Qs[row * 64 + (((kk * 4 + lr) ^ (lc & 7)) * 8)];
      }
#pragma unroll
      for (int nt = 0; nt < 8; nt++) {
        int row = nt * 16 + lc;
        bf16x8 bk = *(const bf16x8*)&Ks[row * 64 + (((kk * 4 + lr) ^ (lc & 7)) * 8)];
#pragma unroll
        for (int mt = 0; mt < 2; mt++)
          s[mt][nt] = __builtin_amdgcn_mfma_f32_16x16x32_bf16(aq[mt], bk, s[mt][nt], 0, 0, 0);
      }
    }
    const bool diag = (kt == qt);
#pragma unroll
    for (int mt = 0; mt < 2; mt++)
#pragma unroll
      for (int nt = 0; nt < 8; nt++)
#pragma unroll
        for (int r = 0; r < 4; r++) {
          float sv = s[mt][nt][r] * SCALE;
          if (diag && (nt * 16 + lc > wave * 32 + mt * 16 + lr * 4 + r)) sv = -__builtin_inff();
          s[mt][nt][r] = sv;
        }
    // online softmax
    float alpha_a[2][4];
#pragma unroll
    for (int mt = 0; mt < 2; mt++)
#pragma unroll
      for (int r = 0; r < 4; r++) {
        float mx = -__builtin_inff();
#pragma unroll
        for (int nt = 0; nt < 8; nt++) mx = fmaxf(mx, s[mt][nt][r]);
        for (int off = 1; off < 16; off <<= 1) mx = fmaxf(mx, __shfl_xor(mx, off));
        float mnew = fmaxf(m_i[mt][r], mx);
        float alpha = exp2f((m_i[mt][r] - mnew) * L2E);
        m_i[mt][r] = mnew;
        float rsum = 0.f;
#pragma unroll
        for (int nt = 0; nt < 8; nt++) {
          float p = exp2f((s[mt][nt][r] - mnew) * L2E);
          s[mt][nt][r] = p;
          rsum += p;
        }
        for (int off = 1; off < 16; off <<= 1) rsum += __shfl_xor(rsum, off);
        l_i[mt][r] = l_i[mt][r] * alpha + rsum;
        alpha_a[mt][r] = alpha;
      }
    // rescale O
#pragma unroll
    for (int mt = 0; mt < 2; mt++)
#pragma unroll
      for (int nt = 0; nt < 4; nt++)
#pragma unroll
        for (int r = 0; r < 4; r++) o_acc[mt][nt][r] *= alpha_a[mt][r];
    // P -> LDS (C-layout to A-layout round trip), swizzled
    const int wbase = wave * 32 * 128;
#pragma unroll
    for (int mt = 0; mt < 2; mt++)
#pragma unroll
      for (int nt = 0; nt < 8; nt++) {
        int g = nt * 2 + (lc >> 3);
#pragma unroll
        for (int r = 0; r < 4; r++) {
          int rowp = mt * 16 + lr * 4 + r;
          Ps[wbase + rowp * 128 + ((g ^ (rowp & 7)) * 8) + (lc & 7)] = f2bf(s[mt][nt][r]);
        }
      }
    // O += P V   (LDS ops within a wave are in-order)
#pragma unroll
    for (int kk = 0; kk < 4; kk++) {
      bf16x8 ap[2];
#pragma unroll
      for (int mt = 0; mt < 2; mt++) {
        int rowp = mt * 16 + lc;
        ap[mt] = *(const bf16x8*)&Ps[wbase + rowp * 128 + (((kk * 4 + lr) ^ (lc & 7)) * 8)];
      }
#pragma unroll
      for (int nt = 0; nt < 4; nt++) {
        int row = nt * 16 + lc;
        bf16x8 bv = *(const bf16x8*)&Vts[row * 128 + (((kk * 4 + lr) ^ (lc & 7)) * 8)];
#pragma unroll
        for (int mt = 0; mt < 2; mt++)
          o_acc[mt][nt] = __builtin_amdgcn_mfma_f32_16x16x32_bf16(ap[mt], bv, o_acc[mt][nt], 0, 0, 0);
      }
    }
  }
  // normalize + store to [b, s, h*64+d]
  float inv[2][4];
#pragma unroll
  for (int mt = 0; mt < 2; mt++)
#pragma unroll
    for (int r = 0; r < 4; r++) inv[mt][r] = 1.f / l_i[mt][r];
#pragma unroll
  for (int mt = 0; mt < 2; mt++)
#pragma unroll
    for (int nt = 0; nt < 4; nt++)
#pragma unroll
      for (int r = 0; r < 4; r++) {
        int sg = Q0 + wave * 32 + mt * 16 + lr * 4 + r;
        int col = h * DK + nt * 16 + lc;
        Ob[((size_t)b * SS + sg) * DM + col] = f2bf(o_acc[mt][nt][r] * inv[mt][r]);
      }
}

extern "C" void kernel_launch(void* const* d_in, const int* in_sizes, int n_in,
                              void* d_out, int out_size, void* d_ws, size_t ws_size,
                              hipStream_t stream) {
  const float* x  = (const float*)d_in[0];
  const float* Wq = (const float*)d_in[1];
  const float* Wk = (const float*)d_in[2];
  const float* Wv = (const float*)d_in[3];
  const float* Wo = (const float*)d_in[4];
  const float* W1 = (const float*)d_in[5];
  const float* b1 = (const float*)d_in[6];
  const float* W2 = (const float*)d_in[7];
  const float* b2 = (const float*)d_in[8];
  const float* g1 = (const float*)d_in[9];
  const float* be1 = (const float*)d_in[10];
  const float* g2 = (const float*)d_in[11];
  const float* be2 = (const float*)d_in[12];

  char* ws = (char*)d_ws;
  unsigned short* WqkvT = (unsigned short*)(ws);                 // 6 MB
  unsigned short* WoT   = (unsigned short*)(ws + 6291456);       // 2 MB
  unsigned short* W1T   = (unsigned short*)(ws + 8388608);       // 8 MB
  unsigned short* W2T   = (unsigned short*)(ws + 16777216);      // 8 MB
  unsigned short* hbuf  = (unsigned short*)(ws + 25165824);      // 16 MB
  unsigned short* Qb    = (unsigned short*)(ws + 41943040);      // 16 MB
  unsigned short* Kb    = (unsigned short*)(ws + 58720256);      // 16 MB
  unsigned short* Vtb   = (unsigned short*)(ws + 75497472);      // 16 MB
  unsigned short* attnO = (unsigned short*)(ws + 92274688);      // 16 MB
  float*          x1    = (float*)(ws + 109051904);              // 32 MB
  unsigned short* ffn1  = (unsigned short*)(ws + 41943040);      // 64 MB, aliases Qb..attnO (dead)

  transpose_all<<<12288, dim3(32, 8), 0, stream>>>(Wq, Wk, Wv, Wo, W1, W2,
                                                   WqkvT, WoT, W1T, W2T);

  ln_bf16<<<8192, 256, 0, stream>>>(x, g1, be1, hbuf);

  gemm_bt<0><<<dim3(24, 64), 256, 0, stream>>>(hbuf, WqkvT, 8192, 3072, 1024,
      nullptr, nullptr, nullptr, nullptr, Qb, Kb, Vtb);

  attn<<<dim3(4, NH, BB), 256, 0, stream>>>(Qb, Kb, Vtb, attnO);

  gemm_bt<1><<<dim3(8, 64), 256, 0, stream>>>(attnO, WoT, 8192, 1024, 1024,
      nullptr, x, x1, nullptr, nullptr, nullptr, nullptr);

  ln_bf16<<<8192, 256, 0, stream>>>(x1, g2, be2, hbuf);

  gemm_bt<2><<<dim3(32, 64), 256, 0, stream>>>(hbuf, W1T, 8192, 4096, 1024,
      b1, nullptr, nullptr, ffn1, nullptr, nullptr, nullptr);

  gemm_bt<3><<<dim3(8, 64), 256, 0, stream>>>(ffn1, W2T, 8192, 1024, 4096,
      b2, x1, (float*)d_out, nullptr, nullptr, nullptr, nullptr);
}